// Round 12
// baseline (3702.108 us; speedup 1.0000x reference)
//
#include <hip/hip_runtime.h>
#include <cmath>
#include <cstdint>

typedef __bf16 bf16;
typedef __bf16 bf16x8 __attribute__((ext_vector_type(8)));
typedef unsigned short u16x8 __attribute__((ext_vector_type(8)));
typedef float f32x4 __attribute__((ext_vector_type(4)));
typedef unsigned u32x4 __attribute__((ext_vector_type(4)));

#define HPOISON 0x7FC07FC0u   // hi-half = bf16 NaN: unreachable for finite h values

static __device__ __forceinline__ float gelu_exact(float x) {
    return 0.5f * x * (1.f + erff(x * 0.70710678118654752f));
}

static __device__ __forceinline__ float fast_sigmoid(float x) {
    return __builtin_amdgcn_rcpf(1.f + __expf(-x));
}
static __device__ __forceinline__ float fast_tanh(float x) {
    // tanh(x) = 1 - 2/(exp(2x)+1); saturates correctly at +-inf
    return 1.f - 2.f * __builtin_amdgcn_rcpf(1.f + __expf(2.f * x));
}

// ---- device-coherent 16B ops (MALL path, proven r9/r11) ----
static __device__ __forceinline__ void store16u_sc1(unsigned* p, u32x4 v) {
    asm volatile("global_store_dwordx4 %0, %1, off sc1" :: "v"(p), "v"(v) : "memory");
}
static __device__ __forceinline__ void load64u_sc1(const unsigned* p, u32x4& a, u32x4& b,
                                                   u32x4& c, u32x4& d) {
    asm volatile(
        "global_load_dwordx4 %0, %4, off sc1\n\t"
        "global_load_dwordx4 %1, %4, off offset:16 sc1\n\t"
        "global_load_dwordx4 %2, %4, off offset:32 sc1\n\t"
        "global_load_dwordx4 %3, %4, off offset:48 sc1\n\t"
        "s_waitcnt vmcnt(0)"
        : "=&v"(a), "=&v"(b), "=&v"(c), "=&v"(d)
        : "v"(p) : "memory");
}

// ---- async global->LDS 16B (m97's lever: compiler never auto-emits this) ----
static __device__ __forceinline__ void gl_lds16(const bf16* g, bf16* l) {
#if defined(__has_builtin) && __has_builtin(__builtin_amdgcn_global_load_lds)
    __builtin_amdgcn_global_load_lds(
        (const unsigned __attribute__((address_space(1)))*)g,
        (unsigned __attribute__((address_space(3)))*)l, 16, 0, 0);
#else
    *(uint4*)l = *(const uint4*)g;   // fallback: register staging (r11 path)
#endif
}

// ---------- fp32 -> bf16 convert of x with SAME padding rows (t=-1 and t=2000 zeroed) ----------
__global__ void cvt_xpad_kernel(const float* __restrict__ x, bf16* __restrict__ xp) {
    int idx = blockIdx.x * 256 + threadIdx.x;
    if (idx >= 8 * 2002 * 128) return;
    int c = idx & 127;
    int rest = idx >> 7;            // b*2002 + tp
    int tp = rest % 2002;
    int b = rest / 2002;
    float v = 0.f;
    if (tp >= 1 && tp <= 2000) v = x[(b * 2000 + tp - 1) * 128 + c];
    xp[idx] = (bf16)v;
}

// ---------- generic transpose+convert: in fp32 [R][C] -> out [C][Rpad], zero pad r in [R,Rpad) ----------
template <typename OT>
__global__ void transpose_cvt_kernel(const float* __restrict__ in, OT* __restrict__ out,
                                     int R, int C, int Rpad) {
    __shared__ float tile[32][33];
    int tx = threadIdx.x & 31, ty = threadIdx.x >> 5;   // 32 x 8
    int r0 = blockIdx.y * 32, c0 = blockIdx.x * 32;
    for (int i = ty; i < 32; i += 8) {
        int r = r0 + i, c = c0 + tx;
        tile[i][tx] = (r < R && c < C) ? in[(size_t)r * C + c] : 0.f;
    }
    __syncthreads();
    for (int i = ty; i < 32; i += 8) {
        int c = c0 + i, r = r0 + tx;
        if (c < C && r < Rpad) out[(size_t)c * Rpad + r] = (OT)tile[tx][i];
    }
}

// ---------- transpose + split fp32 -> (hi, lo) bf16 pair: in [R][C] -> out [C][R] ----------
__global__ void transpose_split_kernel(const float* __restrict__ in, bf16* __restrict__ hi,
                                       bf16* __restrict__ lo, int R, int C) {
    __shared__ float tile[32][33];
    int tx = threadIdx.x & 31, ty = threadIdx.x >> 5;
    int r0 = blockIdx.y * 32, c0 = blockIdx.x * 32;
    for (int i = ty; i < 32; i += 8) {
        int r = r0 + i, c = c0 + tx;
        tile[i][tx] = (r < R && c < C) ? in[(size_t)r * C + c] : 0.f;
    }
    __syncthreads();
    for (int i = ty; i < 32; i += 8) {
        int c = c0 + i, r = r0 + tx;
        if (c < C && r < R) {
            float v = tile[tx][i];
            bf16 h = (bf16)v;
            size_t o = (size_t)c * R + r;
            hi[o] = h;
            lo[o] = (bf16)(v - (float)h);
        }
    }
}

// ---------- zero h1 pad row (t=2000 per batch); needed by gemm<1> ----------
__global__ void zero_aux_kernel(bf16* __restrict__ h1) {
    int idx = blockIdx.x * 256 + threadIdx.x;
    if (idx < 8 * 4096) {
        int b = idx >> 12, n = idx & 4095;
        h1[((size_t)(b * 2001 + 2000)) * 4096 + n] = (bf16)0.f;
    }
}

// ---------- poison-fill hstep (runs AFTER gemm<1> frees the aliased h1 region) ----------
__global__ void poison_kernel(unsigned* __restrict__ hstep) {
    size_t i = (size_t)blockIdx.x * 256 + threadIdx.x;   // one 16B chunk each
    if (i < (size_t)1024 * 4096 / 4) {
        u32x4 pz = {HPOISON, HPOISON, HPOISON, HPOISON};
        *(u32x4*)(hstep + i * 4) = pz;
    }
}

// ---------- unified bf16 MFMA GEMM, 128x128 tile, BK=32, 256 thr (4 waves, each 64x64) ----------
// Staging now uses global_load_lds (async, no VGPR round-trip): LDS dest is linear lane-ordered
// (As + tid*16 within each wave) which is exactly the wave-uniform-base + lane*16 HW pattern.
// MODE 0: conv1  M=16000(b,t)    K=384  (tap,cin)  N=4096  out: gelu -> h1 bf16 [b][t][n]
// MODE 1: conv2  M=8000 (b,t')   K=12288(tap,cin)  N=1024  out: gelu -> h2T bf16 [b][n][t']
// MODE 2: zin    M=8192 (b,s)    K=1024 (f,pad)    N=2048  out: +bias -> Zin fp32 [b][s][n]
template <int MODE>
__launch_bounds__(256)
__global__ void gemm_kernel(const bf16* __restrict__ A, const bf16* __restrict__ BT,
                            const float* __restrict__ bias, void* __restrict__ Cout) {
    constexpr int KTOT = (MODE == 0) ? 384 : (MODE == 1) ? 12288 : 1024;
    constexpr int MTOT = (MODE == 0) ? 16000 : (MODE == 1) ? 8000 : 8192;
    __shared__ __align__(16) bf16 As[128 * 32];
    __shared__ __align__(16) bf16 Bs[128 * 32];
    const int tid = threadIdx.x;
    const int lane = tid & 63, wave = tid >> 6;
    const int m0 = blockIdx.y * 128, n0 = blockIdx.x * 128;
    const int wm = (wave >> 1) * 64, wn = (wave & 1) * 64;

    f32x4 acc[4][4];
#pragma unroll
    for (int mi = 0; mi < 4; ++mi)
#pragma unroll
        for (int ni = 0; ni < 4; ++ni) acc[mi][ni] = (f32x4){0.f, 0.f, 0.f, 0.f};

    for (int kt = 0; kt < KTOT / 32; ++kt) {
        const int k0 = kt * 32;
        __syncthreads();
#pragma unroll
        for (int s = 0; s < 2; ++s) {
            int ch = tid + s * 256;          // 512 chunks of 16B = 8KB tile
            int row = ch >> 2;
            int ko = (ch & 3) * 8;
            int m = m0 + row;
            if (m > MTOT - 1) m = MTOT - 1;
            const bf16* ga;
            if (MODE == 0) {
                int b = m / 2000, t = m - b * 2000;
                ga = A + ((size_t)(b * 2002 + t + (k0 >> 7)) * 128 + (k0 & 127) + ko);
            } else if (MODE == 1) {
                int b = m / 1000, t = m - b * 1000;
                ga = A + ((size_t)(b * 2001 + 2 * t + (k0 >> 12)) * 4096 + (k0 & 4095) + ko);
            } else {
                ga = A + ((size_t)m * 1000 + k0 + ko);   // overruns row end by <=24 elems; B rows are zero there
            }
            gl_lds16(ga, &As[ch * 8]);
            const bf16* gb = BT + ((size_t)(n0 + row) * KTOT + k0 + ko);
            gl_lds16(gb, &Bs[ch * 8]);
        }
        __syncthreads();   // compiler emits vmcnt(0) drain before the barrier
        bf16x8 af[4], bfr[4];
#pragma unroll
        for (int i = 0; i < 4; ++i)
            af[i] = *(const bf16x8*)&As[(wm + i * 16 + (lane & 15)) * 32 + (lane >> 4) * 8];
#pragma unroll
        for (int i = 0; i < 4; ++i)
            bfr[i] = *(const bf16x8*)&Bs[(wn + i * 16 + (lane & 15)) * 32 + (lane >> 4) * 8];
#pragma unroll
        for (int mi = 0; mi < 4; ++mi)
#pragma unroll
            for (int ni = 0; ni < 4; ++ni)
                acc[mi][ni] = __builtin_amdgcn_mfma_f32_16x16x32_bf16(af[mi], bfr[ni], acc[mi][ni], 0, 0, 0);
    }

#pragma unroll
    for (int mi = 0; mi < 4; ++mi) {
        int rb = m0 + wm + mi * 16 + (lane >> 4) * 4;
#pragma unroll
        for (int ni = 0; ni < 4; ++ni) {
            int col = n0 + wn + ni * 16 + (lane & 15);
#pragma unroll
            for (int i = 0; i < 4; ++i) {
                int row = rb + i;
                float v = acc[mi][ni][i];
                if (MODE == 0) {
                    float y = gelu_exact(v + bias[col]);
                    int b = row / 2000, t = row - b * 2000;
                    ((bf16*)Cout)[(size_t)(b * 2001 + t) * 4096 + col] = (bf16)y;
                } else if (MODE == 1) {
                    if (row < 8000) {
                        float y = gelu_exact(v + bias[col]);
                        int b = row / 1000, t = row - b * 1000;
                        ((bf16*)Cout)[(size_t)(b * 1024 + col) * 1000 + t] = (bf16)y;
                    }
                } else {
                    ((float*)Cout)[(size_t)row * 2048 + col] = v + bias[col];
                }
            }
        }
    }
}

// ---------- persistent LSTM: 32 wgs, self-certifying wide-slot exchange, clean vmcnt queue ----
// Changes vs r11 (protocol identical): (1) `out` written by a ROTATING designated wg (w == t&31)
// from its kept polled data (h = hi+lo reconstruction, err <= 2^-17) AFTER its h-store — other
// wgs go h-store -> poll with an empty vmcnt FIFO (the poll's vmcnt(0) no longer waits on out
// store-acks); (2) Zin loaded just-in-time after S1, completing under the MFMA phase. Final row
// t=1023 keeps the exact-hval all-wg path.
__launch_bounds__(256, 1)
__global__ void lstm_persist_kernel(const float* __restrict__ Zin,
                                    const bf16* __restrict__ WrHi,
                                    const bf16* __restrict__ WrLo,
                                    unsigned* __restrict__ hstep,
                                    float* __restrict__ out) {
    __shared__ __align__(16) unsigned char hS[2][8192];    // [plane][8 rows x 512 k] bf16, XOR-swizzled
    __shared__ float zex[4][128];                          // [gate][b*16+u]
    __shared__ float invfS[512];                           // PE inverse-frequency table
    const int tid = threadIdx.x;
    const int wv = tid >> 6;          // wave == gate
    const int w = blockIdx.x;
    const int lane = tid & 63;

    // ---- one-time: Wr B-fragments into registers (16 cols x 512 k x hi/lo = 128 VGPRs) ----
    bf16x8 bh[16], bl[16];
    {
        const size_t cb = (size_t)(wv * 512 + w * 16 + (lane & 15)) * 512 + (lane >> 4) * 8;
#pragma unroll
        for (int kk = 0; kk < 16; ++kk) {
            bh[kk] = *(const bf16x8*)&WrHi[cb + kk * 32];
            bl[kk] = *(const bf16x8*)&WrLo[cb + kk * 32];
        }
    }
    // ---- one-time: PE invf table ----
    for (int i = tid; i < 512; i += 256)
        invfS[i] = powf(10000.f, -(float)(2 * (i >> 1)) * (1.f / 512.f));
    __syncthreads();

    const int b = tid >> 4, u = tid & 15, j = w * 16 + u;  // epilogue mapping (tid<128)
    float c_state = 0.f;

    const int rowsel = lane & 15;       // C col (unit), and A row via &7
    const int kq = lane >> 4;           // k quarter
    const unsigned aswz = (unsigned)((rowsel & 7) << 4);
    const unsigned abase = (unsigned)((rowsel & 7) * 1024);

    // staging indices: thread (srow, scol) reads units [16*scol, 16*scol+16) of batch srow
    const int srow = tid >> 5;
    const int scol = tid & 31;
    const unsigned ssw = (unsigned)((srow & 7) << 4);
    const unsigned sbase = (unsigned)(srow * 1024);

    unsigned keep[16];   // kept copy of this step's polled h (for designated out-write)

    for (int t = 0; t < 1024; ++t) {
        // stage h_{t-1}: poll own 64B until all 16 u32 are non-poison; data IS the readiness
        {
            unsigned vv[16];
            if (t > 0) {
                const unsigned* src = hstep + (size_t)t * 4096 + srow * 512 + scol * 16;
                for (;;) {
                    u32x4 qa, qb, qc, qd;
                    load64u_sc1(src, qa, qb, qc, qd);
#pragma unroll
                    for (int i = 0; i < 4; ++i) {
                        vv[i] = qa[i]; vv[4 + i] = qb[i]; vv[8 + i] = qc[i]; vv[12 + i] = qd[i];
                    }
                    bool ok = true;
#pragma unroll
                    for (int i = 0; i < 16; ++i) ok = ok && (vv[i] != HPOISON);
                    if (ok) break;
                    __builtin_amdgcn_s_sleep(1);   // paced retry; flood-free
                }
            } else {
#pragma unroll
                for (int i = 0; i < 16; ++i) vv[i] = 0u;   // h_{-1} = 0 (bf16 0 bits = 0)
            }
#pragma unroll
            for (int i = 0; i < 16; ++i) keep[i] = vv[i];
            u16x8 h0, h1v, l0, l1v;
#pragma unroll
            for (int i = 0; i < 8; ++i) {
                h0[i]  = (unsigned short)(vv[i] >> 16);
                l0[i]  = (unsigned short)(vv[i] & 0xFFFFu);
                h1v[i] = (unsigned short)(vv[8 + i] >> 16);
                l1v[i] = (unsigned short)(vv[8 + i] & 0xFFFFu);
            }
            unsigned o0 = (unsigned)(scol * 32);
            *(u16x8*)&hS[0][sbase + (o0 ^ ssw)] = h0;
            *(u16x8*)&hS[0][sbase + ((o0 + 16) ^ ssw)] = h1v;
            *(u16x8*)&hS[1][sbase + (o0 ^ ssw)] = l0;
            *(u16x8*)&hS[1][sbase + ((o0 + 16) ^ ssw)] = l1v;
        }
        __syncthreads();   // S1: hS ready
        // JIT Zin load: issues now, completes under the MFMA phase (L2/L3-resident)
        float zin0 = 0.f, zin1 = 0.f, zin2 = 0.f, zin3 = 0.f;
        if (tid < 128) {
            const float* zp = Zin + (size_t)(b * 1024 + t) * 2048;
            zin0 = zp[j]; zin1 = zp[512 + j]; zin2 = zp[1024 + j]; zin3 = zp[1536 + j];
        }
        // z-tile for gate wv: 16 k-steps x 3 products (hh, lh, hl); B operands from registers
        f32x4 acc0 = {0.f, 0.f, 0.f, 0.f}, acc1 = {0.f, 0.f, 0.f, 0.f}, acc2 = {0.f, 0.f, 0.f, 0.f};
#pragma unroll
        for (int kk = 0; kk < 16; ++kk) {
            unsigned ko = (unsigned)((kk * 4 + kq) * 16);
            bf16x8 ah = *(const bf16x8*)&hS[0][abase + (ko ^ aswz)];
            bf16x8 al = *(const bf16x8*)&hS[1][abase + (ko ^ aswz)];
            acc0 = __builtin_amdgcn_mfma_f32_16x16x32_bf16(ah, bh[kk], acc0, 0, 0, 0);
            acc1 = __builtin_amdgcn_mfma_f32_16x16x32_bf16(al, bh[kk], acc1, 0, 0, 0);
            acc2 = __builtin_amdgcn_mfma_f32_16x16x32_bf16(ah, bl[kk], acc2, 0, 0, 0);
        }
        if (kq < 2) {   // valid batch rows 0..7
#pragma unroll
            for (int i = 0; i < 4; ++i)
                zex[wv][(kq * 4 + i) * 16 + rowsel] = acc0[i] + acc1[i] + acc2[i];
        }
        __syncthreads();   // S2: zex ready, all hS reads of this step complete
        if (tid < 128) {
            float zi = zex[0][tid] + zin0;
            float zf = zex[1][tid] + zin1;
            float zg = zex[2][tid] + zin2;
            float zo = zex[3][tid] + zin3;
            float ig = fast_sigmoid(zi);
            float fg = fast_sigmoid(zf);
            float og = fast_sigmoid(zo);
            float c = fg * c_state + ig * fast_tanh(zg);
            c_state = c;
            float hval = og * fast_tanh(c);
            if (t < 1023) {
                // pack (hi,lo) — bit-identical to consumer-side split of fp32 hval
                bf16 hh = (bf16)hval;
                bf16 hlo = (bf16)(hval - (float)hh);
                unsigned pk = ((unsigned)*(unsigned short*)&hh << 16) |
                              (unsigned)*(unsigned short*)&hlo;
                unsigned p1 = (unsigned)__shfl_down((int)pk, 1);
                unsigned p2 = (unsigned)__shfl_down((int)pk, 2);
                unsigned p3 = (unsigned)__shfl_down((int)pk, 3);
                if ((tid & 3) == 0) {
                    u32x4 hv = {pk, p1, p2, p3};
                    store16u_sc1(hstep + (size_t)(t + 1) * 4096 + b * 512 + j, hv);
                }
                // no drain, no flag; nothing else enters this thread's vmcnt queue before
                // the next poll (out-write is the designated wg's job)
            } else {
                // final row: exact hval path (all wgs, own 16 units)
                float ang = 1023.f * invfS[j];
                float pe = (j & 1) ? cosf(ang) : sinf(ang);
                out[(size_t)(b * 1024 + 1023) * 512 + j] = hval + pe;
            }
        }
        // rotating designated wg writes out[:, t-1, :] from kept h_{t-1} (AFTER its h-store)
        if (t > 0 && w == (t & 31)) {
            const float ts = (float)(t - 1);
            float ovals[16];
#pragma unroll
            for (int i = 0; i < 16; ++i) {
                float hi = __uint_as_float(keep[i] & 0xFFFF0000u);
                float lo = __uint_as_float(keep[i] << 16);
                int jj = scol * 16 + i;
                float ang = ts * invfS[jj];
                float pe = (jj & 1) ? cosf(ang) : sinf(ang);
                ovals[i] = hi + lo + pe;
            }
            float* op = out + ((size_t)(srow * 1024) + (t - 1)) * 512 + scol * 16;
#pragma unroll
            for (int q = 0; q < 4; ++q)
                *(f32x4*)(op + q * 4) =
                    (f32x4){ovals[4 * q], ovals[4 * q + 1], ovals[4 * q + 2], ovals[4 * q + 3]};
        }
    }
}

extern "C" void kernel_launch(void* const* d_in, const int* in_sizes, int n_in,
                              void* d_out, int out_size, void* d_ws, size_t ws_size,
                              hipStream_t stream) {
    const float* x  = (const float*)d_in[0];
    const float* w1 = (const float*)d_in[1];
    const float* b1 = (const float*)d_in[2];
    const float* w2 = (const float*)d_in[3];
    const float* b2 = (const float*)d_in[4];
    const float* wk = (const float*)d_in[5];
    const float* wr = (const float*)d_in[6];
    const float* lb = (const float*)d_in[7];
    float* out = (float*)d_out;

    uint8_t* ws = (uint8_t*)d_ws;
    size_t off = 0;
    auto alloc = [&](size_t bytes) {
        void* p = ws + off;
        off += (bytes + 255) & ~(size_t)255;
        return p;
    };
    bf16* xpad = (bf16*)alloc((size_t)8 * 2002 * 128 * 2);
    bf16* W1T  = (bf16*)alloc((size_t)4096 * 384 * 2);
    bf16* W2T  = (bf16*)alloc((size_t)1024 * 12288 * 2);
    bf16* WkT  = (bf16*)alloc((size_t)2048 * 1024 * 2);
    bf16* WrHi = (bf16*)alloc((size_t)2048 * 512 * 2);
    bf16* WrLo = (bf16*)alloc((size_t)2048 * 512 * 2);
    bf16* h1   = (bf16*)alloc((size_t)8 * 2001 * 4096 * 2);
    bf16* h2T  = (bf16*)alloc((size_t)8 * 1024 * 1000 * 2 + 256);  // +slack for k-tail overread
    float* Zin = (float*)alloc((size_t)8 * 1024 * 2048 * 4);
    // hstep u32[1024][8][512] (16.8MB) ALIASED onto h1 (131MB, dead after gemm<1>) —
    // a separate allocation would overflow the ~255.5MB workspace (r8 crash).
    unsigned* hstep = (unsigned*)h1;

    cvt_xpad_kernel<<<(8 * 2002 * 128 + 255) / 256, 256, 0, stream>>>(x, xpad);
    transpose_cvt_kernel<bf16><<<dim3(128, 12), 256, 0, stream>>>(w1, W1T, 384, 4096, 384);
    transpose_cvt_kernel<bf16><<<dim3(32, 384), 256, 0, stream>>>(w2, W2T, 12288, 1024, 12288);
    transpose_cvt_kernel<bf16><<<dim3(64, 32), 256, 0, stream>>>(wk, WkT, 1000, 2048, 1024);
    transpose_split_kernel<<<dim3(64, 16), 256, 0, stream>>>(wr, WrHi, WrLo, 512, 2048);
    zero_aux_kernel<<<(8 * 4096 + 255) / 256, 256, 0, stream>>>(h1);

    gemm_kernel<0><<<dim3(32, 125), 256, 0, stream>>>(xpad, W1T, b1, (void*)h1);
    gemm_kernel<1><<<dim3(8, 63), 256, 0, stream>>>(h1, W2T, b2, (void*)h2T);
    // h1 now dead -> poison-fill the aliased hstep slots (off the LSTM critical path)
    poison_kernel<<<4096, 256, 0, stream>>>(hstep);
    gemm_kernel<2><<<dim3(16, 64), 256, 0, stream>>>(h2T, WkT, lb, (void*)Zin);

    lstm_persist_kernel<<<32, 256, 0, stream>>>(Zin, WrHi, WrLo, hstep, out);
}

// Round 13
// 3227.011 us; speedup vs baseline: 1.1472x; 1.1472x over previous
//
#include <hip/hip_runtime.h>
#include <cmath>
#include <cstdint>

typedef __bf16 bf16;
typedef __bf16 bf16x8 __attribute__((ext_vector_type(8)));
typedef unsigned short u16x8 __attribute__((ext_vector_type(8)));
typedef float f32x4 __attribute__((ext_vector_type(4)));
typedef unsigned u32x4 __attribute__((ext_vector_type(4)));

#define HPOISON 0x7FC07FC0u   // hi-half = bf16 NaN: unreachable for finite h values

static __device__ __forceinline__ float gelu_exact(float x) {
    return 0.5f * x * (1.f + erff(x * 0.70710678118654752f));
}

static __device__ __forceinline__ float fast_sigmoid(float x) {
    return __builtin_amdgcn_rcpf(1.f + __expf(-x));
}
static __device__ __forceinline__ float fast_tanh(float x) {
    // tanh(x) = 1 - 2/(exp(2x)+1); saturates correctly at +-inf
    return 1.f - 2.f * __builtin_amdgcn_rcpf(1.f + __expf(2.f * x));
}

// ---- device-coherent 16B ops (MALL path, proven r9/r11) ----
static __device__ __forceinline__ void store16u_sc1(unsigned* p, u32x4 v) {
    asm volatile("global_store_dwordx4 %0, %1, off sc1" :: "v"(p), "v"(v) : "memory");
}
static __device__ __forceinline__ void load64u_sc1(const unsigned* p, u32x4& a, u32x4& b,
                                                   u32x4& c, u32x4& d) {
    asm volatile(
        "global_load_dwordx4 %0, %4, off sc1\n\t"
        "global_load_dwordx4 %1, %4, off offset:16 sc1\n\t"
        "global_load_dwordx4 %2, %4, off offset:32 sc1\n\t"
        "global_load_dwordx4 %3, %4, off offset:48 sc1\n\t"
        "s_waitcnt vmcnt(0)"
        : "=&v"(a), "=&v"(b), "=&v"(c), "=&v"(d)
        : "v"(p) : "memory");
}

// ---- async global->LDS 16B (kept from r12: neutral-to-positive) ----
static __device__ __forceinline__ void gl_lds16(const bf16* g, bf16* l) {
#if defined(__has_builtin) && __has_builtin(__builtin_amdgcn_global_load_lds)
    __builtin_amdgcn_global_load_lds(
        (const unsigned __attribute__((address_space(1)))*)g,
        (unsigned __attribute__((address_space(3)))*)l, 16, 0, 0);
#else
    *(uint4*)l = *(const uint4*)g;   // fallback: register staging (r11 path)
#endif
}

// ---------- fp32 -> bf16 convert of x with SAME padding rows (t=-1 and t=2000 zeroed) ----------
__global__ void cvt_xpad_kernel(const float* __restrict__ x, bf16* __restrict__ xp) {
    int idx = blockIdx.x * 256 + threadIdx.x;
    if (idx >= 8 * 2002 * 128) return;
    int c = idx & 127;
    int rest = idx >> 7;            // b*2002 + tp
    int tp = rest % 2002;
    int b = rest / 2002;
    float v = 0.f;
    if (tp >= 1 && tp <= 2000) v = x[(b * 2000 + tp - 1) * 128 + c];
    xp[idx] = (bf16)v;
}

// ---------- generic transpose+convert: in fp32 [R][C] -> out [C][Rpad], zero pad r in [R,Rpad) ----------
template <typename OT>
__global__ void transpose_cvt_kernel(const float* __restrict__ in, OT* __restrict__ out,
                                     int R, int C, int Rpad) {
    __shared__ float tile[32][33];
    int tx = threadIdx.x & 31, ty = threadIdx.x >> 5;   // 32 x 8
    int r0 = blockIdx.y * 32, c0 = blockIdx.x * 32;
    for (int i = ty; i < 32; i += 8) {
        int r = r0 + i, c = c0 + tx;
        tile[i][tx] = (r < R && c < C) ? in[(size_t)r * C + c] : 0.f;
    }
    __syncthreads();
    for (int i = ty; i < 32; i += 8) {
        int c = c0 + i, r = r0 + tx;
        if (c < C && r < Rpad) out[(size_t)c * Rpad + r] = (OT)tile[tx][i];
    }
}

// ---------- transpose + split fp32 -> (hi, lo) bf16 pair: in [R][C] -> out [C][R] ----------
__global__ void transpose_split_kernel(const float* __restrict__ in, bf16* __restrict__ hi,
                                       bf16* __restrict__ lo, int R, int C) {
    __shared__ float tile[32][33];
    int tx = threadIdx.x & 31, ty = threadIdx.x >> 5;
    int r0 = blockIdx.y * 32, c0 = blockIdx.x * 32;
    for (int i = ty; i < 32; i += 8) {
        int r = r0 + i, c = c0 + tx;
        tile[i][tx] = (r < R && c < C) ? in[(size_t)r * C + c] : 0.f;
    }
    __syncthreads();
    for (int i = ty; i < 32; i += 8) {
        int c = c0 + i, r = r0 + tx;
        if (c < C && r < R) {
            float v = tile[tx][i];
            bf16 h = (bf16)v;
            size_t o = (size_t)c * R + r;
            hi[o] = h;
            lo[o] = (bf16)(v - (float)h);
        }
    }
}

// ---------- bf16 transpose: h2 natural [b][1000][1024] -> h2T [b][1024][1000] ----------
// Coalesced on both sides via LDS tile; replaces conv2's scattered 2B epilogue stores.
__global__ void transpose_h2_kernel(const bf16* __restrict__ in, bf16* __restrict__ out) {
    __shared__ bf16 tile[32][33];
    int tx = threadIdx.x & 31, ty = threadIdx.x >> 5;   // 32 x 8
    int b = blockIdx.z;
    int t0 = blockIdx.x * 32, n0 = blockIdx.y * 32;
    for (int i = ty; i < 32; i += 8) {
        int t = t0 + i;
        tile[i][tx] = (t < 1000) ? in[((size_t)(b * 1000 + t)) * 1024 + n0 + tx] : (bf16)0.f;
    }
    __syncthreads();
    for (int i = ty; i < 32; i += 8) {
        int n = n0 + i, t = t0 + tx;
        if (t < 1000) out[((size_t)(b * 1024 + n)) * 1000 + t] = tile[tx][i];
    }
}

// ---------- zero h1 pad row (t=2000 per batch); needed by gemm<1> ----------
__global__ void zero_aux_kernel(bf16* __restrict__ h1) {
    int idx = blockIdx.x * 256 + threadIdx.x;
    if (idx < 8 * 4096) {
        int b = idx >> 12, n = idx & 4095;
        h1[((size_t)(b * 2001 + 2000)) * 4096 + n] = (bf16)0.f;
    }
}

// ---------- poison-fill hstep (runs AFTER gemm<1> frees the aliased h1 region) ----------
__global__ void poison_kernel(unsigned* __restrict__ hstep) {
    size_t i = (size_t)blockIdx.x * 256 + threadIdx.x;   // one 16B chunk each
    if (i < (size_t)1024 * 4096 / 4) {
        u32x4 pz = {HPOISON, HPOISON, HPOISON, HPOISON};
        *(u32x4*)(hstep + i * 4) = pz;
    }
}

// ---------- unified bf16 MFMA GEMM, 128x128 tile, BK=32, 256 thr (4 waves, each 64x64) ----------
// MODE 0: conv1  M=16000(b,t)    K=384  (tap,cin)  N=4096  out: gelu -> h1 bf16 [b][t][n]
// MODE 1: conv2  M=8000 (b,t')   K=12288(tap,cin)  N=1024  out: gelu -> h2 bf16 [b][t'][n] (NATURAL, coalesced)
// MODE 2: zin    M=8192 (b,s)    K=1024 (f,pad)    N=2048  out: +bias -> Zin fp32 [b][s][n]
template <int MODE>
__launch_bounds__(256)
__global__ void gemm_kernel(const bf16* __restrict__ A, const bf16* __restrict__ BT,
                            const float* __restrict__ bias, void* __restrict__ Cout) {
    constexpr int KTOT = (MODE == 0) ? 384 : (MODE == 1) ? 12288 : 1024;
    constexpr int MTOT = (MODE == 0) ? 16000 : (MODE == 1) ? 8000 : 8192;
    __shared__ __align__(16) bf16 As[128 * 32];
    __shared__ __align__(16) bf16 Bs[128 * 32];
    const int tid = threadIdx.x;
    const int lane = tid & 63, wave = tid >> 6;
    const int m0 = blockIdx.y * 128, n0 = blockIdx.x * 128;
    const int wm = (wave >> 1) * 64, wn = (wave & 1) * 64;

    f32x4 acc[4][4];
#pragma unroll
    for (int mi = 0; mi < 4; ++mi)
#pragma unroll
        for (int ni = 0; ni < 4; ++ni) acc[mi][ni] = (f32x4){0.f, 0.f, 0.f, 0.f};

    for (int kt = 0; kt < KTOT / 32; ++kt) {
        const int k0 = kt * 32;
        __syncthreads();
#pragma unroll
        for (int s = 0; s < 2; ++s) {
            int ch = tid + s * 256;          // 512 chunks of 16B = 8KB tile
            int row = ch >> 2;
            int ko = (ch & 3) * 8;
            int m = m0 + row;
            if (m > MTOT - 1) m = MTOT - 1;
            const bf16* ga;
            if (MODE == 0) {
                int b = m / 2000, t = m - b * 2000;
                ga = A + ((size_t)(b * 2002 + t + (k0 >> 7)) * 128 + (k0 & 127) + ko);
            } else if (MODE == 1) {
                int b = m / 1000, t = m - b * 1000;
                ga = A + ((size_t)(b * 2001 + 2 * t + (k0 >> 12)) * 4096 + (k0 & 4095) + ko);
            } else {
                ga = A + ((size_t)m * 1000 + k0 + ko);   // overruns row end by <=24 elems; B rows are zero there
            }
            gl_lds16(ga, &As[ch * 8]);
            const bf16* gb = BT + ((size_t)(n0 + row) * KTOT + k0 + ko);
            gl_lds16(gb, &Bs[ch * 8]);
        }
        __syncthreads();   // compiler emits vmcnt(0) drain before the barrier
        bf16x8 af[4], bfr[4];
#pragma unroll
        for (int i = 0; i < 4; ++i)
            af[i] = *(const bf16x8*)&As[(wm + i * 16 + (lane & 15)) * 32 + (lane >> 4) * 8];
#pragma unroll
        for (int i = 0; i < 4; ++i)
            bfr[i] = *(const bf16x8*)&Bs[(wn + i * 16 + (lane & 15)) * 32 + (lane >> 4) * 8];
#pragma unroll
        for (int mi = 0; mi < 4; ++mi)
#pragma unroll
            for (int ni = 0; ni < 4; ++ni)
                acc[mi][ni] = __builtin_amdgcn_mfma_f32_16x16x32_bf16(af[mi], bfr[ni], acc[mi][ni], 0, 0, 0);
    }

#pragma unroll
    for (int mi = 0; mi < 4; ++mi) {
        int rb = m0 + wm + mi * 16 + (lane >> 4) * 4;
#pragma unroll
        for (int ni = 0; ni < 4; ++ni) {
            int col = n0 + wn + ni * 16 + (lane & 15);
#pragma unroll
            for (int i = 0; i < 4; ++i) {
                int row = rb + i;
                float v = acc[mi][ni][i];
                if (MODE == 0) {
                    float y = gelu_exact(v + bias[col]);
                    int b = row / 2000, t = row - b * 2000;
                    ((bf16*)Cout)[(size_t)(b * 2001 + t) * 4096 + col] = (bf16)y;
                } else if (MODE == 1) {
                    if (row < 8000) {
                        float y = gelu_exact(v + bias[col]);
                        ((bf16*)Cout)[(size_t)row * 1024 + col] = (bf16)y;   // natural, coalesced
                    }
                } else {
                    ((float*)Cout)[(size_t)row * 2048 + col] = v + bias[col];
                }
            }
        }
    }
}

// ---------- persistent LSTM: 32 wgs, self-certifying wide-slot exchange, Wr in registers ----------
// (verbatim r11 structure — the 2610us-proven version; r12's out-rotation/JIT-Zin reverted)
__launch_bounds__(256, 1)
__global__ void lstm_persist_kernel(const float* __restrict__ Zin,
                                    const bf16* __restrict__ WrHi,
                                    const bf16* __restrict__ WrLo,
                                    unsigned* __restrict__ hstep,
                                    float* __restrict__ out) {
    __shared__ __align__(16) unsigned char hS[2][8192];    // [plane][8 rows x 512 k] bf16, XOR-swizzled
    __shared__ float zex[4][128];                          // [gate][b*16+u]
    const int tid = threadIdx.x;
    const int wv = tid >> 6;          // wave == gate
    const int w = blockIdx.x;
    const int lane = tid & 63;

    // ---- one-time: Wr B-fragments into registers (16 cols x 512 k x hi/lo = 128 VGPRs) ----
    bf16x8 bh[16], bl[16];
    {
        const size_t cb = (size_t)(wv * 512 + w * 16 + (lane & 15)) * 512 + (lane >> 4) * 8;
#pragma unroll
        for (int kk = 0; kk < 16; ++kk) {
            bh[kk] = *(const bf16x8*)&WrHi[cb + kk * 32];
            bl[kk] = *(const bf16x8*)&WrLo[cb + kk * 32];
        }
    }

    const int b = tid >> 4, u = tid & 15, j = w * 16 + u;  // epilogue mapping (tid<128)
    float c_state = 0.f;
    float zin0 = 0.f, zin1 = 0.f, zin2 = 0.f, zin3 = 0.f;
    const float invf = powf(10000.f, -(float)(2 * (j >> 1)) * (1.f / 512.f));
    if (tid < 128) {
        const float* zp = Zin + (size_t)(b * 1024) * 2048;
        zin0 = zp[j]; zin1 = zp[512 + j]; zin2 = zp[1024 + j]; zin3 = zp[1536 + j];
    }

    const int rowsel = lane & 15;       // C col (unit), and A row via &7
    const int kq = lane >> 4;           // k quarter
    const unsigned aswz = (unsigned)((rowsel & 7) << 4);
    const unsigned abase = (unsigned)((rowsel & 7) * 1024);

    // staging indices: thread (srow, scol) reads units [16*scol, 16*scol+16) of batch srow
    const int srow = tid >> 5;
    const int scol = tid & 31;
    const unsigned ssw = (unsigned)((srow & 7) << 4);
    const unsigned sbase = (unsigned)(srow * 1024);

    for (int t = 0; t < 1024; ++t) {
        // stage h_{t-1}: poll own 64B until all 16 u32 are non-poison; data IS the readiness
        {
            unsigned vv[16];
            if (t > 0) {
                const unsigned* src = hstep + (size_t)t * 4096 + srow * 512 + scol * 16;
                for (;;) {
                    u32x4 qa, qb, qc, qd;
                    load64u_sc1(src, qa, qb, qc, qd);
#pragma unroll
                    for (int i = 0; i < 4; ++i) {
                        vv[i] = qa[i]; vv[4 + i] = qb[i]; vv[8 + i] = qc[i]; vv[12 + i] = qd[i];
                    }
                    bool ok = true;
#pragma unroll
                    for (int i = 0; i < 16; ++i) ok = ok && (vv[i] != HPOISON);
                    if (ok) break;
                    __builtin_amdgcn_s_sleep(1);   // paced retry; flood-free
                }
            } else {
#pragma unroll
                for (int i = 0; i < 16; ++i) vv[i] = 0u;   // h_{-1} = 0 (bf16 0 bits = 0)
            }
            u16x8 h0, h1v, l0, l1v;
#pragma unroll
            for (int i = 0; i < 8; ++i) {
                h0[i]  = (unsigned short)(vv[i] >> 16);
                l0[i]  = (unsigned short)(vv[i] & 0xFFFFu);
                h1v[i] = (unsigned short)(vv[8 + i] >> 16);
                l1v[i] = (unsigned short)(vv[8 + i] & 0xFFFFu);
            }
            unsigned o0 = (unsigned)(scol * 32);
            *(u16x8*)&hS[0][sbase + (o0 ^ ssw)] = h0;
            *(u16x8*)&hS[0][sbase + ((o0 + 16) ^ ssw)] = h1v;
            *(u16x8*)&hS[1][sbase + (o0 ^ ssw)] = l0;
            *(u16x8*)&hS[1][sbase + ((o0 + 16) ^ ssw)] = l1v;
        }
        __syncthreads();   // S1: hS ready
        // z-tile for gate wv: 16 k-steps x 3 products (hh, lh, hl); B operands from registers
        f32x4 acc0 = {0.f, 0.f, 0.f, 0.f}, acc1 = {0.f, 0.f, 0.f, 0.f}, acc2 = {0.f, 0.f, 0.f, 0.f};
#pragma unroll
        for (int kk = 0; kk < 16; ++kk) {
            unsigned ko = (unsigned)((kk * 4 + kq) * 16);
            bf16x8 ah = *(const bf16x8*)&hS[0][abase + (ko ^ aswz)];
            bf16x8 al = *(const bf16x8*)&hS[1][abase + (ko ^ aswz)];
            acc0 = __builtin_amdgcn_mfma_f32_16x16x32_bf16(ah, bh[kk], acc0, 0, 0, 0);
            acc1 = __builtin_amdgcn_mfma_f32_16x16x32_bf16(al, bh[kk], acc1, 0, 0, 0);
            acc2 = __builtin_amdgcn_mfma_f32_16x16x32_bf16(ah, bl[kk], acc2, 0, 0, 0);
        }
        if (kq < 2) {   // valid batch rows 0..7
#pragma unroll
            for (int i = 0; i < 4; ++i)
                zex[wv][(kq * 4 + i) * 16 + rowsel] = acc0[i] + acc1[i] + acc2[i];
        }
        __syncthreads();   // S2: zex ready, all hS reads of this step complete
        if (tid < 128) {
            float zi = zex[0][tid] + zin0;
            float zf = zex[1][tid] + zin1;
            float zg = zex[2][tid] + zin2;
            float zo = zex[3][tid] + zin3;
            float ig = fast_sigmoid(zi);
            float fg = fast_sigmoid(zf);
            float og = fast_sigmoid(zo);
            float c = fg * c_state + ig * fast_tanh(zg);
            c_state = c;
            float hval = og * fast_tanh(c);
            if (t < 1023) {
                // pack (hi,lo) — bit-identical to consumer-side split of fp32 hval
                bf16 hh = (bf16)hval;
                bf16 hlo = (bf16)(hval - (float)hh);
                unsigned pk = ((unsigned)*(unsigned short*)&hh << 16) |
                              (unsigned)*(unsigned short*)&hlo;
                unsigned p1 = (unsigned)__shfl_down((int)pk, 1);
                unsigned p2 = (unsigned)__shfl_down((int)pk, 2);
                unsigned p3 = (unsigned)__shfl_down((int)pk, 3);
                if ((tid & 3) == 0) {
                    u32x4 hv = {pk, p1, p2, p3};
                    store16u_sc1(hstep + (size_t)(t + 1) * 4096 + b * 512 + j, hv);
                }
                // no drain, no flag: the store itself certifies readiness at the consumer
            }
            // off-critical-path: output + PE, next-step Zin prefetch (overlaps the poll wait)
            float ang = (float)t * invf;
            float pe = (j & 1) ? cosf(ang) : sinf(ang);
            out[(size_t)(b * 1024 + t) * 512 + j] = hval + pe;
            if (t < 1023) {
                const float* zp = Zin + (size_t)(b * 1024 + t + 1) * 2048;
                zin0 = zp[j]; zin1 = zp[512 + j]; zin2 = zp[1024 + j]; zin3 = zp[1536 + j];
            }
        }
    }
}

extern "C" void kernel_launch(void* const* d_in, const int* in_sizes, int n_in,
                              void* d_out, int out_size, void* d_ws, size_t ws_size,
                              hipStream_t stream) {
    const float* x  = (const float*)d_in[0];
    const float* w1 = (const float*)d_in[1];
    const float* b1 = (const float*)d_in[2];
    const float* w2 = (const float*)d_in[3];
    const float* b2 = (const float*)d_in[4];
    const float* wk = (const float*)d_in[5];
    const float* wr = (const float*)d_in[6];
    const float* lb = (const float*)d_in[7];
    float* out = (float*)d_out;

    uint8_t* ws = (uint8_t*)d_ws;
    size_t off = 0;
    auto alloc = [&](size_t bytes) {
        void* p = ws + off;
        off += (bytes + 255) & ~(size_t)255;
        return p;
    };
    bf16* xpad = (bf16*)alloc((size_t)8 * 2002 * 128 * 2);
    bf16* W1T  = (bf16*)alloc((size_t)4096 * 384 * 2);
    bf16* W2T  = (bf16*)alloc((size_t)1024 * 12288 * 2);
    bf16* WkT  = (bf16*)alloc((size_t)2048 * 1024 * 2);
    bf16* WrHi = (bf16*)alloc((size_t)2048 * 512 * 2);
    bf16* WrLo = (bf16*)alloc((size_t)2048 * 512 * 2);
    bf16* h1   = (bf16*)alloc((size_t)8 * 2001 * 4096 * 2);
    bf16* h2T  = (bf16*)alloc((size_t)8 * 1024 * 1000 * 2 + 256);  // +slack for k-tail overread
    float* Zin = (float*)alloc((size_t)8 * 1024 * 2048 * 4);
    // hstep u32[1024][8][512] (16.8MB) ALIASED onto h1 (dead after gemm<1>) — r8 overflow lesson.
    unsigned* hstep = (unsigned*)h1;
    // h2 natural [8][1000][1024] bf16 (16.4MB) ALIASED onto Zin (written by gemm<2> only AFTER
    // transpose_h2 has consumed h2nat) — zero extra workspace.
    bf16* h2nat = (bf16*)Zin;

    cvt_xpad_kernel<<<(8 * 2002 * 128 + 255) / 256, 256, 0, stream>>>(x, xpad);
    transpose_cvt_kernel<bf16><<<dim3(128, 12), 256, 0, stream>>>(w1, W1T, 384, 4096, 384);
    transpose_cvt_kernel<bf16><<<dim3(32, 384), 256, 0, stream>>>(w2, W2T, 12288, 1024, 12288);
    transpose_cvt_kernel<bf16><<<dim3(64, 32), 256, 0, stream>>>(wk, WkT, 1000, 2048, 1024);
    transpose_split_kernel<<<dim3(64, 16), 256, 0, stream>>>(wr, WrHi, WrLo, 512, 2048);
    zero_aux_kernel<<<(8 * 4096 + 255) / 256, 256, 0, stream>>>(h1);

    gemm_kernel<0><<<dim3(32, 125), 256, 0, stream>>>(xpad, W1T, b1, (void*)h1);
    gemm_kernel<1><<<dim3(8, 63), 256, 0, stream>>>(h1, W2T, b2, (void*)h2nat);
    transpose_h2_kernel<<<dim3(32, 32, 8), 256, 0, stream>>>(h2nat, h2T);
    // h1 now dead -> poison-fill the aliased hstep slots (off the LSTM critical path)
    poison_kernel<<<4096, 256, 0, stream>>>(hstep);
    gemm_kernel<2><<<dim3(16, 64), 256, 0, stream>>>(h2T, WkT, lb, (void*)Zin);

    lstm_persist_kernel<<<32, 256, 0, stream>>>(Zin, WrHi, WrLo, hstep, out);
}